// Round 10
// baseline (233.257 us; speedup 1.0000x reference)
//
#include <hip/hip_runtime.h>
#include <math.h>

#define NUM_A 90
#define RBINS 727      // 2*363 + 1
#define HDIM  256
#define WDIM  256
#define RMIN  181      // lowest bin ever touched
#define RACT  365      // active bins: 181..545
#define TPB   768      // 384 bins x 2 strips = 12 waves
#define PH_ROWS 64
#define PHFLOATS (PH_ROWS * 256)   // 16384 floats = 64 KB

typedef float f2 __attribute__((ext_vector_type(2)));

static __device__ __forceinline__ f2 fma2(f2 a, f2 b, f2 c) {
#if __has_builtin(__builtin_elementwise_fma)
    return __builtin_elementwise_fma(a, b, c);
#else
    return f2{fmaf(a.x, b.x, c.x), fmaf(a.y, b.y, c.y)};
#endif
}
static __device__ __forceinline__ f2 max2(f2 a, f2 b) {
#if __has_builtin(__builtin_elementwise_max)
    return __builtin_elementwise_max(a, b);
#else
    return f2{fmaxf(a.x, b.x), fmaxf(a.y, b.y)};
#endif
}

// ---------------- angle table: tab[2a]=cos, tab[2a+1]=sin ----------------
__global__ void angles_k(float* __restrict__ tab) {
    int a = threadIdx.x;
    if (a < NUM_A) {
        double th = (double)a * (3.14159265358979323846 / 90.0);
        tab[2 * a]     = (float)cos(th);
        tab[2 * a + 1] = (float)sin(th);
    }
}

// ---------------- transpose: maskT[b][x][y] = mask[b][y][x] ----------------
__global__ __launch_bounds__(256) void transpose_k(const float* __restrict__ in,
                                                   float* __restrict__ out) {
    __shared__ float tile[32][33];
    int b = blockIdx.z;
    const float* ib = in  + (size_t)b * (HDIM * WDIM);
    float*       ob = out + (size_t)b * (HDIM * WDIM);
    int x0 = blockIdx.x * 32, y0 = blockIdx.y * 32;
    int tx = threadIdx.x, ty = threadIdx.y;
#pragma unroll
    for (int j = ty; j < 32; j += 8)
        tile[j][tx] = ib[(size_t)(y0 + j) * WDIM + (x0 + tx)];
    __syncthreads();
#pragma unroll
    for (int j = ty; j < 32; j += 8)
        ob[(size_t)(x0 + j) * HDIM + (y0 + tx)] = tile[tx][j];
}

// ---------------- LDS-staged gather hough, SMALL-coeff solve axis ----------------
// t = (i-128)ci + (j-128)cj + 363 with |ci| = min(|c|,s) (solve axis, contiguous
// in the chosen layout) and |cj| = max >= 0.707. Per task (bin r, row j) the
// window |t-r|<1 spans NT ~ 2/|ci| contiguous taps: wave-uniform trip count,
// ds_read_b64 pairs, packed-f32 triangle weights w = max(0, 1-|u|) that
// self-zero out-of-window and out-of-margin taps. Window start clamped by one
// med3 into [0, 256-NT] (even) -> no LDS pads needed. ci==0 (a=0): invci=0
// makes wlo=0, med3(...,0,0)=0, NT=256, u row-constant -- generic path works.
__global__ __launch_bounds__(TPB, 2) void hough_lds_k(const float* __restrict__ srcA,
                                                      const float* __restrict__ srcB,
                                                      const float* __restrict__ tab,
                                                      float* __restrict__ out) {
    __shared__ float tile[PHFLOATS];
    int ba = blockIdx.x;
    int b  = ba / NUM_A;
    int a  = ba - b * NUM_A;

    float c = tab[2 * a], s = tab[2 * a + 1];
    // solve axis = SMALLER coeff; pick layout so solve axis is contiguous.
    // natural mask: x contiguous (solve x, ci=c); maskT: y contiguous (solve y, ci=s)
    bool  xsolve = fabsf(c) <= fabsf(s);
    float ci = xsolve ? c : s;
    float cj = xsolve ? s : c;          // |cj| >= 0.707
    const float* src = (xsolve ? srcA : srcB) + (size_t)b * (HDIM * WDIM);

    int   tid = threadIdx.x;
    int   bin = tid >> 1;               // 2 strips per bin
    int   m   = tid & 1;
    int   r   = RMIN + bin;
    float rf  = (float)r;
    bool  active = bin < RACT;

    float ca   = fabsf(ci);
    bool  isZ  = ca < 1e-6f;
    float invci = isZ ? 0.0f : (1.0f / ci);
    int   NT   = isZ ? 256 : (((int)(2.0f / ca) + 7) & ~3);
    if (NT > 256) NT = 256;
    int   NT4  = NT >> 2;
    float limNTh = (float)((256 - NT) >> 1);

    // active j-range: rows whose in-image t-span [base+p, base+q] hits (r-1,r+1)
    float p = fminf(-128.0f * ci, 127.0f * ci);
    float q = fmaxf(-128.0f * ci, 127.0f * ci);
    float invj = 1.0f / cj;             // |cj| >= 0.707, never ~0
    float jA = (rf + 1.0f - p - 363.0f) * invj + 128.0f;
    float jB = (rf - 1.0f - q - 363.0f) * invj + 128.0f;
    float jmn = fminf(jA, jB) - 1.0f;   // widen: stray rows self-zero (w=0)
    float jmx = fmaxf(jA, jB) + 2.0f;
    int jl = (int)fminf(fmaxf(jmn, 0.0f), 256.0f);
    int jh = (int)fminf(fmaxf(jmx, 0.0f), 256.0f);
    if (!active) { jl = 0; jh = 0; }
    int len = jh - jl;
    int ls = jl + ((m * len) >> 1);     // exact strip partition
    int le = jl + (((m + 1) * len) >> 1);

    float Z0   = 363.0f - rf - 128.0f * (ci + cj);
    float winw = 2.0f * invci;          // signed window width (0 for isZ)
    float db1  = -cj * invci;           // d(b1)/dj
    float ci2  = ci + ci, ci3 = ci2 + ci;
    const f2 cq4  = {ci2 + ci2, ci2 + ci2};
    const f2 onev = {1.0f, 1.0f};
    const f2 zerov = {0.0f, 0.0f};

    f2 accA = {0.0f, 0.0f}, accB = {0.0f, 0.0f};
    for (int ph = 0; ph < 4; ++ph) {
        if (ph) __syncthreads();        // prior-phase LDS reads complete
        const float* gph = src + ph * PHFLOATS;
        for (int u = tid; u < PHFLOATS / 4; u += TPB) {
            __builtin_amdgcn_global_load_lds(
                (const __attribute__((address_space(1))) unsigned int*)gph + (size_t)u * 4,
                (__attribute__((address_space(3))) unsigned int*)tile + (size_t)u * 4,
                16, 0, 0);
        }
        __syncthreads();                // staging complete

        int phb = ph << 6;
        int jsp = ls > phb ? ls : phb;
        int jep = le < phb + PH_ROWS ? le : phb + PH_ROWS;

        float jf = (float)jsp;
        float Zj = fmaf(jf, cj, Z0);
        float b1 = (-1.0f - Zj) * invci;
        int rowaddr = (jsp - phb) << 8;
        for (int j = jsp; j < jep; ++j) {
            float wlo = fminf(b1, b1 + winw);
            float fh  = floorf(wlo * 0.5f);
            fh = __builtin_amdgcn_fmed3f(fh, 0.0f, limNTh);
            float isf = fh + fh;
            int   is  = ((int)fh) << 1;
            float u0  = fmaf(isf, ci, Zj);
            f2 uA = {u0, u0 + ci};
            f2 uB = {u0 + ci2, u0 + ci3};
            int addr = rowaddr + is;
            for (int t = 0; t < NT4; ++t) {
                f2 mA = *(const f2*)(tile + addr);
                f2 mB = *(const f2*)(tile + addr + 2);
                f2 aA = max2(uA, -uA);
                f2 aB = max2(uB, -uB);
                f2 wA = max2(onev - aA, zerov);
                f2 wB = max2(onev - aB, zerov);
                accA = fma2(mA, wA, accA);
                accB = fma2(mB, wB, accB);
                uA += cq4; uB += cq4;
                addr += 4;
            }
            Zj += cj; b1 += db1; rowaddr += 256;
        }
    }

    float acc = (accA.x + accA.y) + (accB.x + accB.y);
    acc += __shfl_xor(acc, 1);          // reduce the 2 strips
    if (active && m == 0)
        out[(size_t)ba * RBINS + r] = acc;
}

// ---------------- fallback (no workspace): R7-proven global-gather ----------------
typedef float f3v __attribute__((ext_vector_type(3)));
typedef f3v __attribute__((aligned(4))) f3u;
#define FB_GRP (368 * 4)

__global__ __launch_bounds__(256) void hough_fb_k(const float* __restrict__ src0,
                                                  float* __restrict__ out, int nba) {
    int gtid = blockIdx.x * 256 + threadIdx.x;
    int grp  = gtid / FB_GRP;
    if (grp >= nba) return;
    int k    = gtid - grp * FB_GRP;
    int ba   = __builtin_amdgcn_readfirstlane(grp);
    int b    = ba / NUM_A;
    int a    = ba - b * NUM_A;
    double th = (double)a * (3.14159265358979323846 / 90.0);
    float c = (float)cos(th), s = (float)sin(th);
    bool  xs = fabsf(c) >= fabsf(s);
    float ci = xs ? c : s, cj = xs ? s : c;
    const float* src = src0 + (size_t)b * (HDIM * WDIM);
    int   bin = k >> 2, m = k & 3;
    int   r = RMIN + bin;
    float rf = (float)r;
    bool  active = bin < RACT;
    float inv = 1.0f / ci, ainv = fabsf(inv);
    float p = fminf(-128.0f * ci, 127.0f * ci);
    float q = fmaxf(-128.0f * ci, 127.0f * ci);
    int jl, jh;
    float acj = fabsf(cj);
    if (acj > 1e-5f) {
        float invj = 1.0f / cj;
        float jA = (rf + 1.0f - p - 363.0f) * invj + 128.0f;
        float jB = (rf - 1.0f - q - 363.0f) * invj + 128.0f;
        jl = (int)fminf(fmaxf(fminf(jA, jB) - 1.0f, 0.0f), 256.0f);
        jh = (int)fminf(fmaxf(fmaxf(jA, jB) + 2.0f, 0.0f), 256.0f);
    } else {
        bool any = (363.0f + q > rf - 1.01f) && (363.0f + p < rf + 1.01f);
        jl = 0; jh = any ? 256 : 0;
    }
    if (!active) { jl = 0; jh = 0; }
    int len = jh - jl;
    int js = jl + ((m * len) >> 2);
    int je = jl + (((m + 1) * len) >> 2);
    float dlo = -cj * inv;
    float LO0 = 128.0f + (rf - 363.0f) * inv - ainv + 128.0f * cj * inv;
    float Z0  = 363.0f - rf - 128.0f * cj - 128.0f * ci;
    float ci2 = ci + ci;
    float acc = 0.0f;
    for (int j = js; j < je; ++j) {
        float jf  = (float)j;
        float lo0 = fmaf(jf, dlo, LO0);
        float z0  = fmaf(jf, cj, Z0);
        float f0  = __builtin_amdgcn_fmed3f(ceilf(lo0), 0.0f, 253.0f);
        int   i0  = (int)f0;
        float a0, b0, c0;
        if (xs) {
            f3v mm = *(const f3u*)(src + ((size_t)j << 8) + i0);
            a0 = mm.x; b0 = mm.y; c0 = mm.z;
        } else {
            const float* p0 = src + j + ((size_t)i0 << 8);
            a0 = p0[0]; b0 = p0[256]; c0 = p0[512];
        }
        float u0 = fmaf(f0, ci, z0);
        acc = fmaf(a0, fmaxf(1.0f - fabsf(u0), 0.0f), acc);
        acc = fmaf(b0, fmaxf(1.0f - fabsf(u0 + ci), 0.0f), acc);
        acc = fmaf(c0, fmaxf(1.0f - fabsf(u0 + ci2), 0.0f), acc);
    }
    acc += __shfl_xor(acc, 1);
    acc += __shfl_xor(acc, 2);
    if (active && m == 0)
        out[(size_t)ba * RBINS + r] = acc;
}

extern "C" void kernel_launch(void* const* d_in, const int* in_sizes, int n_in,
                              void* d_out, int out_size, void* d_ws, size_t ws_size,
                              hipStream_t stream) {
    const float* mask = (const float*)d_in[0];
    float* out = (float*)d_out;
    int B = in_sizes[0] / (HDIM * WDIM);   // 16
    int nba = B * NUM_A;

    size_t needT = (size_t)B * HDIM * WDIM * sizeof(float);
    size_t needW = needT + 2 * NUM_A * sizeof(float);
    int fast = (d_ws != nullptr && ws_size >= needW) ? 1 : 0;
    float* maskT = (float*)d_ws;
    float* tab   = (float*)((char*)d_ws + needT);

    // zero the never-touched rho bins once per call (also covers len==0 bins)
    hipMemsetAsync(d_out, 0, (size_t)out_size * sizeof(float), stream);

    if (fast) {
        transpose_k<<<dim3(WDIM / 32, HDIM / 32, B), dim3(32, 8), 0, stream>>>(mask, maskT);
        angles_k<<<1, 128, 0, stream>>>(tab);
        hough_lds_k<<<nba, TPB, 0, stream>>>(mask, maskT, tab, out);
    } else {
        int nthreads = nba * FB_GRP;
        hough_fb_k<<<(nthreads + 255) / 256, 256, 0, stream>>>(mask, out, nba);
    }
}

// Round 11
// 114.957 us; speedup vs baseline: 2.0291x; 2.0291x over previous
//
#include <hip/hip_runtime.h>
#include <math.h>

#define NUM_A 90
#define RBINS 727      // 2*363 + 1
#define HDIM  256
#define WDIM  256
#define RMIN  181      // lowest bin ever touched
#define RACT  365      // active bins: 181..545
#define TPB   768      // 368 bins x 2 strips (+pad) = 12 waves
#define PHROWS   64
#define PHFLOATS (PHROWS * 256)   // 16384 floats = 64 KB

// ---------------- angle table: tab[2a]=cos, tab[2a+1]=sin ----------------
__global__ void angles_k(float* __restrict__ tab) {
    int a = threadIdx.x;
    if (a < NUM_A) {
        double th = (double)a * (3.14159265358979323846 / 90.0);
        tab[2 * a]     = (float)cos(th);
        tab[2 * a + 1] = (float)sin(th);
    }
}

// ---------------- transpose: maskT[b][x][y] = mask[b][y][x] ----------------
__global__ __launch_bounds__(256) void transpose_k(const float* __restrict__ in,
                                                   float* __restrict__ out) {
    __shared__ float tile[32][33];
    int b = blockIdx.z;
    const float* ib = in  + (size_t)b * (HDIM * WDIM);
    float*       ob = out + (size_t)b * (HDIM * WDIM);
    int x0 = blockIdx.x * 32, y0 = blockIdx.y * 32;
    int tx = threadIdx.x, ty = threadIdx.y;
#pragma unroll
    for (int j = ty; j < 32; j += 8)
        tile[j][tx] = ib[(size_t)(y0 + j) * WDIM + (x0 + tx)];
    __syncthreads();
#pragma unroll
    for (int j = ty; j < 32; j += 8)
        ob[(size_t)(x0 + j) * HDIM + (y0 + tx)] = tile[tx][j];
}

// ---------------- LDS-staged gather hough (R8 skeleton) ----------------
// One block per (b,a). 4 phases: stage 64 solve-layout rows (64 KB) into LDS,
// then each lane (bin r, strip m of 2) reads its 3 taps per row from LDS.
// Weight identity: max(0, 1-|u|) = med3(1-u, 1+u, 0)  -- one v_med3_f32,
// fully self-clamping (correct even when the 3-tap stencil was med3-clamped
// at an image edge: clamped taps get |u|>=1 -> w=0).
// (a,b) = (1-u, 1+u) steps across taps by -/+ci; derived per row from
// frac = f0 - lo (exact) via 2 fmas -- no z tracking.
__global__ __launch_bounds__(TPB, 6) void hough_lds_k(const float* __restrict__ srcA,
                                                      const float* __restrict__ srcB,
                                                      const float* __restrict__ tab,
                                                      float* __restrict__ out) {
    __shared__ float tile[PHFLOATS];
    int ba = blockIdx.x;
    int b  = ba / NUM_A;
    int a  = ba - b * NUM_A;

    float c = tab[2 * a], s = tab[2 * a + 1];
    bool  xs = fabsf(c) >= fabsf(s);       // solve axis = larger coeff
    float ci = xs ? c : s;
    float cj = xs ? s : c;
    const float* src = (xs ? srcA : srcB) + (size_t)b * (HDIM * WDIM);

    int   tid = threadIdx.x;
    int   bin = tid >> 1;                  // 2 strips per bin
    int   m   = tid & 1;
    int   r   = RMIN + bin;
    float rf  = (float)r;
    bool  active = bin < RACT;

    // active j-range: rows whose in-image t-span [base+p, base+q] hits (r-1,r+1)
    float p = fminf(-128.0f * ci, 127.0f * ci);
    float q = fmaxf(-128.0f * ci, 127.0f * ci);
    int jl, jh;
    float acj = fabsf(cj);
    if (acj > 1e-5f) {
        float invj = 1.0f / cj;
        float jA = (rf + 1.0f - p - 363.0f) * invj + 128.0f;
        float jB = (rf - 1.0f - q - 363.0f) * invj + 128.0f;
        float jmn = fminf(jA, jB) - 1.0f;   // widen: weights self-guard extras
        float jmx = fmaxf(jA, jB) + 2.0f;
        jl = (int)fminf(fmaxf(jmn, 0.0f), 256.0f);
        jh = (int)fminf(fmaxf(jmx, 0.0f), 256.0f);
    } else {                               // cj ~ 0: t j-independent
        bool any = (363.0f + q > rf - 1.01f) && (363.0f + p < rf + 1.01f);
        jl = 0; jh = any ? 256 : 0;
    }
    if (!active) { jl = 0; jh = 0; }
    int len = jh - jl;

    // EXACT strip partition (no overlap, no gap, no padding rows)
    int ls = jl + ((m * len) >> 1);
    int le = jl + (((m + 1) * len) >> 1);

    // lower i-edge of the |u|<1 window: L(j) = LO0 + j*dlo, where u(L) = sgn
    // (sgn = -1 for ci>0, +1 for ci<0); u(i) = sgn + (i - L)*ci.
    float inv  = 1.0f / ci;                // |ci| >= 0.707
    float sgn  = (ci > 0.0f) ? -1.0f : 1.0f;
    float Z0   = 363.0f - rf - 128.0f * cj - 128.0f * ci;
    float LO0  = (sgn - Z0) * inv;
    float dlo  = -cj * inv;
    float onems = 1.0f - sgn;              // 2 (POS) or 0 (NEG)
    float onepls = 1.0f + sgn;             // 0 (POS) or 2 (NEG)
    float dlo2 = dlo + dlo, dlo3 = dlo2 + dlo;

    float acc = 0.0f;
    for (int ph = 0; ph < 4; ++ph) {
        if (ph) __syncthreads();           // prior-phase LDS reads complete
        // stage rows [ph*64, ph*64+64): linear, wave-lane-contiguous 16B units
        const float* gph = src + ph * PHFLOATS;
        for (int u = tid; u < PHFLOATS / 4; u += TPB) {
            __builtin_amdgcn_global_load_lds(
                (const __attribute__((address_space(1))) unsigned int*)gph + (size_t)u * 4,
                (__attribute__((address_space(3))) unsigned int*)tile + (size_t)u * 4,
                16, 0, 0);
        }
        __syncthreads();                   // staging complete (vmcnt drained)

        int ph64 = ph << 6;
        int jsp = ls > ph64 ? ls : ph64;
        int jep = le < ph64 + 64 ? le : ph64 + 64;
        if (jep <= jsp) continue;

        int j = jsp;
        int jend4 = jsp + ((jep - jsp) & ~3);
        for (; j < jend4; j += 4) {
            float jf  = (float)j;
            float lo0 = fmaf(jf, dlo, LO0);
            float lo1 = lo0 + dlo, lo2 = lo0 + dlo2, lo3 = lo0 + dlo3;

            float f0 = __builtin_amdgcn_fmed3f(ceilf(lo0), 0.0f, 253.0f);
            float f1 = __builtin_amdgcn_fmed3f(ceilf(lo1), 0.0f, 253.0f);
            float f2 = __builtin_amdgcn_fmed3f(ceilf(lo2), 0.0f, 253.0f);
            float f3 = __builtin_amdgcn_fmed3f(ceilf(lo3), 0.0f, 253.0f);
            int i0 = (int)f0, i1 = (int)f1, i2 = (int)f2, i3 = (int)f3;

            int rw = (j - ph64) << 8;
            const float* p0 = tile + rw + i0;
            const float* p1 = tile + rw + 256 + i1;
            const float* p2 = tile + rw + 512 + i2;
            const float* p3 = tile + rw + 768 + i3;
            float v00 = p0[0], v01 = p0[1], v02 = p0[2];
            float v10 = p1[0], v11 = p1[1], v12 = p1[2];
            float v20 = p2[0], v21 = p2[1], v22 = p2[2];
            float v30 = p3[0], v31 = p3[1], v32 = p3[2];

            // row 0: (a,b) = (1-u, 1+u) at tap0, step -/+ci per tap
            float fr0 = f0 - lo0;
            float a0 = fmaf(fr0, -ci, onems), b0 = fmaf(fr0, ci, onepls);
            acc = fmaf(v00, __builtin_amdgcn_fmed3f(a0, b0, 0.0f), acc);
            float a0b = a0 - ci, b0b = b0 + ci;
            acc = fmaf(v01, __builtin_amdgcn_fmed3f(a0b, b0b, 0.0f), acc);
            acc = fmaf(v02, __builtin_amdgcn_fmed3f(a0b - ci, b0b + ci, 0.0f), acc);
            // row 1
            float fr1 = f1 - lo1;
            float a1 = fmaf(fr1, -ci, onems), b1 = fmaf(fr1, ci, onepls);
            acc = fmaf(v10, __builtin_amdgcn_fmed3f(a1, b1, 0.0f), acc);
            float a1b = a1 - ci, b1b = b1 + ci;
            acc = fmaf(v11, __builtin_amdgcn_fmed3f(a1b, b1b, 0.0f), acc);
            acc = fmaf(v12, __builtin_amdgcn_fmed3f(a1b - ci, b1b + ci, 0.0f), acc);
            // row 2
            float fr2 = f2 - lo2;
            float a2 = fmaf(fr2, -ci, onems), b2 = fmaf(fr2, ci, onepls);
            acc = fmaf(v20, __builtin_amdgcn_fmed3f(a2, b2, 0.0f), acc);
            float a2b = a2 - ci, b2b = b2 + ci;
            acc = fmaf(v21, __builtin_amdgcn_fmed3f(a2b, b2b, 0.0f), acc);
            acc = fmaf(v22, __builtin_amdgcn_fmed3f(a2b - ci, b2b + ci, 0.0f), acc);
            // row 3
            float fr3 = f3 - lo3;
            float a3 = fmaf(fr3, -ci, onems), b3 = fmaf(fr3, ci, onepls);
            acc = fmaf(v30, __builtin_amdgcn_fmed3f(a3, b3, 0.0f), acc);
            float a3b = a3 - ci, b3b = b3 + ci;
            acc = fmaf(v31, __builtin_amdgcn_fmed3f(a3b, b3b, 0.0f), acc);
            acc = fmaf(v32, __builtin_amdgcn_fmed3f(a3b - ci, b3b + ci, 0.0f), acc);
        }
        for (; j < jep; ++j) {             // tail: <=3 rows per phase
            float jf  = (float)j;
            float lo0 = fmaf(jf, dlo, LO0);
            float f0  = __builtin_amdgcn_fmed3f(ceilf(lo0), 0.0f, 253.0f);
            int   i0  = (int)f0;
            const float* p0 = tile + ((j - ph64) << 8) + i0;
            float v00 = p0[0], v01 = p0[1], v02 = p0[2];
            float fr0 = f0 - lo0;
            float a0 = fmaf(fr0, -ci, onems), b0 = fmaf(fr0, ci, onepls);
            acc = fmaf(v00, __builtin_amdgcn_fmed3f(a0, b0, 0.0f), acc);
            float a0b = a0 - ci, b0b = b0 + ci;
            acc = fmaf(v01, __builtin_amdgcn_fmed3f(a0b, b0b, 0.0f), acc);
            acc = fmaf(v02, __builtin_amdgcn_fmed3f(a0b - ci, b0b + ci, 0.0f), acc);
        }
    }

    // reduce the 2 strips (adjacent lanes), lane m==0 stores
    acc += __shfl_xor(acc, 1);
    if (active && m == 0)
        out[(size_t)ba * RBINS + r] = acc;
}

// ---------------- fallback (no workspace): R7-proven global-gather ----------------
typedef float f3v __attribute__((ext_vector_type(3)));
typedef f3v __attribute__((aligned(4))) f3u;
#define FB_GRP (368 * 4)

__global__ __launch_bounds__(256) void hough_fb_k(const float* __restrict__ src0,
                                                  float* __restrict__ out, int nba) {
    int gtid = blockIdx.x * 256 + threadIdx.x;
    int grp  = gtid / FB_GRP;
    if (grp >= nba) return;
    int k    = gtid - grp * FB_GRP;
    int ba   = __builtin_amdgcn_readfirstlane(grp);
    int b    = ba / NUM_A;
    int a    = ba - b * NUM_A;
    double th = (double)a * (3.14159265358979323846 / 90.0);
    float c = (float)cos(th), s = (float)sin(th);
    bool  xs = fabsf(c) >= fabsf(s);
    float ci = xs ? c : s, cj = xs ? s : c;
    const float* src = src0 + (size_t)b * (HDIM * WDIM);
    int   bin = k >> 2, m = k & 3;
    int   r = RMIN + bin;
    float rf = (float)r;
    bool  active = bin < RACT;
    float inv = 1.0f / ci, ainv = fabsf(inv);
    float p = fminf(-128.0f * ci, 127.0f * ci);
    float q = fmaxf(-128.0f * ci, 127.0f * ci);
    int jl, jh;
    float acj = fabsf(cj);
    if (acj > 1e-5f) {
        float invj = 1.0f / cj;
        float jA = (rf + 1.0f - p - 363.0f) * invj + 128.0f;
        float jB = (rf - 1.0f - q - 363.0f) * invj + 128.0f;
        jl = (int)fminf(fmaxf(fminf(jA, jB) - 1.0f, 0.0f), 256.0f);
        jh = (int)fminf(fmaxf(fmaxf(jA, jB) + 2.0f, 0.0f), 256.0f);
    } else {
        bool any = (363.0f + q > rf - 1.01f) && (363.0f + p < rf + 1.01f);
        jl = 0; jh = any ? 256 : 0;
    }
    if (!active) { jl = 0; jh = 0; }
    int len = jh - jl;
    int js = jl + ((m * len) >> 2);
    int je = jl + (((m + 1) * len) >> 2);
    float dlo = -cj * inv;
    float LO0 = 128.0f + (rf - 363.0f) * inv - ainv + 128.0f * cj * inv;
    float Z0  = 363.0f - rf - 128.0f * cj - 128.0f * ci;
    float ci2 = ci + ci;
    float acc = 0.0f;
    for (int j = js; j < je; ++j) {
        float jf  = (float)j;
        float lo0 = fmaf(jf, dlo, LO0);
        float z0  = fmaf(jf, cj, Z0);
        float f0  = __builtin_amdgcn_fmed3f(ceilf(lo0), 0.0f, 253.0f);
        int   i0  = (int)f0;
        float a0, b0, c0;
        if (xs) {
            f3v mm = *(const f3u*)(src + ((size_t)j << 8) + i0);
            a0 = mm.x; b0 = mm.y; c0 = mm.z;
        } else {
            const float* p0 = src + j + ((size_t)i0 << 8);
            a0 = p0[0]; b0 = p0[256]; c0 = p0[512];
        }
        float u0 = fmaf(f0, ci, z0);
        acc = fmaf(a0, fmaxf(1.0f - fabsf(u0), 0.0f), acc);
        acc = fmaf(b0, fmaxf(1.0f - fabsf(u0 + ci), 0.0f), acc);
        acc = fmaf(c0, fmaxf(1.0f - fabsf(u0 + ci2), 0.0f), acc);
    }
    acc += __shfl_xor(acc, 1);
    acc += __shfl_xor(acc, 2);
    if (active && m == 0)
        out[(size_t)ba * RBINS + r] = acc;
}

extern "C" void kernel_launch(void* const* d_in, const int* in_sizes, int n_in,
                              void* d_out, int out_size, void* d_ws, size_t ws_size,
                              hipStream_t stream) {
    const float* mask = (const float*)d_in[0];
    float* out = (float*)d_out;
    int B = in_sizes[0] / (HDIM * WDIM);   // 16
    int nba = B * NUM_A;

    size_t needT = (size_t)B * HDIM * WDIM * sizeof(float);
    size_t needW = needT + 2 * NUM_A * sizeof(float);
    int fast = (d_ws != nullptr && ws_size >= needW) ? 1 : 0;
    float* maskT = (float*)d_ws;
    float* tab   = (float*)((char*)d_ws + needT);

    // zero the never-touched rho bins once per call (also covers len==0 bins)
    hipMemsetAsync(d_out, 0, (size_t)out_size * sizeof(float), stream);

    if (fast) {
        transpose_k<<<dim3(WDIM / 32, HDIM / 32, B), dim3(32, 8), 0, stream>>>(mask, maskT);
        angles_k<<<1, 128, 0, stream>>>(tab);
        hough_lds_k<<<nba, TPB, 0, stream>>>(mask, maskT, tab, out);
    } else {
        int nthreads = nba * FB_GRP;
        hough_fb_k<<<(nthreads + 255) / 256, 256, 0, stream>>>(mask, out, nba);
    }
}

// Round 13
// 74.366 us; speedup vs baseline: 3.1366x; 1.5458x over previous
//
#include <hip/hip_runtime.h>
#include <math.h>

#define NUM_A 90
#define RBINS 727      // 2*363 + 1
#define HDIM  256
#define WDIM  256
#define RMIN  181      // lowest bin ever touched
#define RACT  365      // active bins: 181..545
#define TPB   768      // 368 bins x 2 parity-strips (+pad) = 12 waves
#define PH_ROWS 52
#define ROWSTR  260    // floats per row slot; 1040 B (16B-aligned); 260 % 32 = 4
#define NPH     5      // 52*4 + 48 = 256
#define TILE_N  (PH_ROWS * ROWSTR)   // 13520 floats = 54080 B

// ---------------- angle table: tab[2a]=cos, tab[2a+1]=sin ----------------
__global__ void angles_k(float* __restrict__ tab) {
    int a = threadIdx.x;
    if (a < NUM_A) {
        double th = (double)a * (3.14159265358979323846 / 90.0);
        tab[2 * a]     = (float)cos(th);
        tab[2 * a + 1] = (float)sin(th);
    }
}

// ---------------- transpose: maskT[b][x][y] = mask[b][y][x] ----------------
__global__ __launch_bounds__(256) void transpose_k(const float* __restrict__ in,
                                                   float* __restrict__ out) {
    __shared__ float tile[32][33];
    int b = blockIdx.z;
    const float* ib = in  + (size_t)b * (HDIM * WDIM);
    float*       ob = out + (size_t)b * (HDIM * WDIM);
    int x0 = blockIdx.x * 32, y0 = blockIdx.y * 32;
    int tx = threadIdx.x, ty = threadIdx.y;
#pragma unroll
    for (int j = ty; j < 32; j += 8)
        tile[j][tx] = ib[(size_t)(y0 + j) * WDIM + (x0 + tx)];
    __syncthreads();
#pragma unroll
    for (int j = ty; j < 32; j += 8)
        ob[(size_t)(x0 + j) * HDIM + (y0 + tx)] = tile[tx][j];
}

// 3-tap weight+accumulate: w_k = med3(1-u_k, 1+u_k, 0), u from fr = f0 - lo
// (exact). R11-proven (absmax 1.0, graph-replay stable).
static __device__ __forceinline__ float tap3(float f0, float lo, float ci,
                                             float onems, float onepls,
                                             float v0, float v1, float v2,
                                             float acc) {
    float fr = f0 - lo;
    float a0 = fmaf(fr, -ci, onems), b0 = fmaf(fr, ci, onepls);
    acc = fmaf(v0, __builtin_amdgcn_fmed3f(a0, b0, 0.0f), acc);
    float a1 = a0 - ci, b1 = b0 + ci;
    acc = fmaf(v1, __builtin_amdgcn_fmed3f(a1, b1, 0.0f), acc);
    float a2 = a1 - ci, b2 = b1 + ci;
    acc = fmaf(v2, __builtin_amdgcn_fmed3f(a2, b2, 0.0f), acc);
    return acc;
}

// ---------------- LDS-staged gather hough (R11 math + parity strips + 260 stride)
__global__ __launch_bounds__(TPB, 6) void hough_lds_k(const float* __restrict__ srcA,
                                                      const float* __restrict__ srcB,
                                                      const float* __restrict__ tab,
                                                      float* __restrict__ out) {
    __shared__ float tile[TILE_N];
    int ba = blockIdx.x;
    int b  = ba / NUM_A;
    int a  = ba - b * NUM_A;

    float c = tab[2 * a], s = tab[2 * a + 1];
    bool  xs = fabsf(c) >= fabsf(s);       // solve axis = larger coeff
    float ci = xs ? c : s;
    float cj = xs ? s : c;
    const float* src = (xs ? srcA : srcB) + (size_t)b * (HDIM * WDIM);

    int   tid = threadIdx.x;
    int   bin = tid >> 1;                  // 2 parity strips per bin
    int   m   = tid & 1;                   // lane parity: rows j with (j&1)==par
    int   r   = RMIN + bin;
    float rf  = (float)r;
    bool  active = bin < RACT;

    // active j-range (R8/R11-proven): rows whose t-span hits (r-1, r+1)
    float p = fminf(-128.0f * ci, 127.0f * ci);
    float q = fmaxf(-128.0f * ci, 127.0f * ci);
    int jl, jh;
    float acj = fabsf(cj);
    if (acj > 1e-5f) {
        float invj = 1.0f / cj;
        float jA = (rf + 1.0f - p - 363.0f) * invj + 128.0f;
        float jB = (rf - 1.0f - q - 363.0f) * invj + 128.0f;
        float jmn = fminf(jA, jB) - 1.0f;   // widen: weights self-guard extras
        float jmx = fmaxf(jA, jB) + 2.0f;
        jl = (int)fminf(fmaxf(jmn, 0.0f), 256.0f);
        jh = (int)fminf(fmaxf(jmx, 0.0f), 256.0f);
    } else {                               // cj ~ 0: t j-independent
        bool any = (363.0f + q > rf - 1.01f) && (363.0f + p < rf + 1.01f);
        jl = 0; jh = any ? 256 : 0;
    }
    if (!active) { jl = 0; jh = 0; }

    // parity strip: EXACT disjoint partition, no boundary arithmetic
    int start = jl + ((jl ^ m) & 1);       // first row >= jl with parity m

    // lower i-edge of the |u|<1 window: L(j) = LO0 + j*dlo; u(L) = sgn
    float inv  = 1.0f / ci;                // |ci| >= 0.707
    float sgn  = (ci > 0.0f) ? -1.0f : 1.0f;
    float Z0   = 363.0f - rf - 128.0f * cj - 128.0f * ci;
    float LO0  = (sgn - Z0) * inv;
    float dlo  = -cj * inv;                // |dlo| <= 1
    float onems = 1.0f - sgn;              // 2 (ci>0) or 0 (ci<0)
    float onepls = 1.0f + sgn;             // 0 (ci>0) or 2 (ci<0)
    float dlo2 = dlo + dlo;

    int wid = tid >> 6, lane = tid & 63;
    float acc = 0.0f;
    for (int ph = 0; ph < NPH; ++ph) {
        int phb   = ph * PH_ROWS;
        int nrows = (phb + PH_ROWS <= 256) ? PH_ROWS : (256 - phb);
        if (ph) __syncthreads();           // prior-phase LDS reads complete
        // stage: one wave stages one 256-float row (64 lanes x 16B);
        // dest base = tile + sl*260 floats = sl*1040 B (16B-aligned)
        for (int sl = wid; sl < nrows; sl += 12) {
            const float* grow = src + (size_t)(phb + sl) * 256 + lane * 4;
            float* lrow = tile + sl * ROWSTR + lane * 4;
            __builtin_amdgcn_global_load_lds(
                (const __attribute__((address_space(1))) unsigned int*)grow,
                (__attribute__((address_space(3))) unsigned int*)lrow, 16, 0, 0);
        }
        __syncthreads();                   // staging complete (vmcnt drained)

        // this lane's parity-m rows within the phase band
        int pstart = phb + ((phb ^ m) & 1);
        int jsp = start > pstart ? start : pstart;
        int jep = jh < phb + nrows ? jh : phb + nrows;
        if (jep <= jsp) continue;
        int cnt = (jep - jsp + 1) >> 1;    // rows: jsp, jsp+2, ...

        float lo = fmaf((float)jsp, dlo, LO0);
        int rowf = (jsp - phb) * ROWSTR;
        int k = 0;
        int npair = cnt >> 1;
        for (int pr = 0; pr < npair; ++pr, k += 2) {
            float lo0 = lo;
            float lo1 = lo + dlo2;
            lo = lo1 + dlo2;
            float f0 = __builtin_amdgcn_fmed3f(ceilf(lo0), 0.0f, 253.0f);
            float f1 = __builtin_amdgcn_fmed3f(ceilf(lo1), 0.0f, 253.0f);
            int i0 = (int)f0, i1 = (int)f1;
            const float* p0 = tile + rowf + i0;
            const float* p1 = tile + rowf + 2 * ROWSTR + i1;
            rowf += 4 * ROWSTR;
            float v00 = p0[0], v01 = p0[1], v02 = p0[2];
            float v10 = p1[0], v11 = p1[1], v12 = p1[2];
            acc = tap3(f0, lo0, ci, onems, onepls, v00, v01, v02, acc);
            acc = tap3(f1, lo1, ci, onems, onepls, v10, v11, v12, acc);
        }
        if (cnt & 1) {                     // tail: one row
            float f0 = __builtin_amdgcn_fmed3f(ceilf(lo), 0.0f, 253.0f);
            int   i0 = (int)f0;
            const float* p0 = tile + rowf + i0;
            float v00 = p0[0], v01 = p0[1], v02 = p0[2];
            acc = tap3(f0, lo, ci, onems, onepls, v00, v01, v02, acc);
        }
    }

    // reduce the 2 parity strips (adjacent lanes), lane m==0 stores
    acc += __shfl_xor(acc, 1);
    if (active && m == 0)
        out[(size_t)ba * RBINS + r] = acc;
}

// ---------------- fallback (no workspace): R7-proven global-gather ----------------
typedef float f3v __attribute__((ext_vector_type(3)));
typedef f3v __attribute__((aligned(4))) f3u;
#define FB_GRP (368 * 4)

__global__ __launch_bounds__(256) void hough_fb_k(const float* __restrict__ src0,
                                                  float* __restrict__ out, int nba) {
    int gtid = blockIdx.x * 256 + threadIdx.x;
    int grp  = gtid / FB_GRP;
    if (grp >= nba) return;
    int k    = gtid - grp * FB_GRP;
    int ba   = __builtin_amdgcn_readfirstlane(grp);
    int b    = ba / NUM_A;
    int a    = ba - b * NUM_A;
    double th = (double)a * (3.14159265358979323846 / 90.0);
    float c = (float)cos(th), s = (float)sin(th);
    bool  xs = fabsf(c) >= fabsf(s);
    float ci = xs ? c : s, cj = xs ? s : c;
    const float* src = src0 + (size_t)b * (HDIM * WDIM);
    int   bin = k >> 2, m = k & 3;
    int   r = RMIN + bin;
    float rf = (float)r;
    bool  active = bin < RACT;
    float inv = 1.0f / ci, ainv = fabsf(inv);
    float p = fminf(-128.0f * ci, 127.0f * ci);
    float q = fmaxf(-128.0f * ci, 127.0f * ci);
    int jl, jh;
    float acj = fabsf(cj);
    if (acj > 1e-5f) {
        float invj = 1.0f / cj;
        float jA = (rf + 1.0f - p - 363.0f) * invj + 128.0f;
        float jB = (rf - 1.0f - q - 363.0f) * invj + 128.0f;
        jl = (int)fminf(fmaxf(fminf(jA, jB) - 1.0f, 0.0f), 256.0f);
        jh = (int)fminf(fmaxf(fmaxf(jA, jB) + 2.0f, 0.0f), 256.0f);
    } else {
        bool any = (363.0f + q > rf - 1.01f) && (363.0f + p < rf + 1.01f);
        jl = 0; jh = any ? 256 : 0;
    }
    if (!active) { jl = 0; jh = 0; }
    int len = jh - jl;
    int js = jl + ((m * len) >> 2);
    int je = jl + (((m + 1) * len) >> 2);
    float dlo = -cj * inv;
    float LO0 = 128.0f + (rf - 363.0f) * inv - ainv + 128.0f * cj * inv;
    float Z0  = 363.0f - rf - 128.0f * cj - 128.0f * ci;
    float ci2 = ci + ci;
    float acc = 0.0f;
    for (int j = js; j < je; ++j) {
        float jf  = (float)j;
        float lo0 = fmaf(jf, dlo, LO0);
        float z0  = fmaf(jf, cj, Z0);
        float f0  = __builtin_amdgcn_fmed3f(ceilf(lo0), 0.0f, 253.0f);
        int   i0  = (int)f0;
        float a0, b0, c0;
        if (xs) {
            f3v mm = *(const f3u*)(src + ((size_t)j << 8) + i0);
            a0 = mm.x; b0 = mm.y; c0 = mm.z;
        } else {
            const float* p0 = src + j + ((size_t)i0 << 8);
            a0 = p0[0]; b0 = p0[256]; c0 = p0[512];
        }
        float u0 = fmaf(f0, ci, z0);
        acc = fmaf(a0, fmaxf(1.0f - fabsf(u0), 0.0f), acc);
        acc = fmaf(b0, fmaxf(1.0f - fabsf(u0 + ci), 0.0f), acc);
        acc = fmaf(c0, fmaxf(1.0f - fabsf(u0 + ci2), 0.0f), acc);
    }
    acc += __shfl_xor(acc, 1);
    acc += __shfl_xor(acc, 2);
    if (active && m == 0)
        out[(size_t)ba * RBINS + r] = acc;
}

extern "C" void kernel_launch(void* const* d_in, const int* in_sizes, int n_in,
                              void* d_out, int out_size, void* d_ws, size_t ws_size,
                              hipStream_t stream) {
    const float* mask = (const float*)d_in[0];
    float* out = (float*)d_out;
    int B = in_sizes[0] / (HDIM * WDIM);   // 16
    int nba = B * NUM_A;

    size_t needT = (size_t)B * HDIM * WDIM * sizeof(float);
    size_t needW = needT + 2 * NUM_A * sizeof(float);
    int fast = (d_ws != nullptr && ws_size >= needW) ? 1 : 0;
    float* maskT = (float*)d_ws;
    float* tab   = (float*)((char*)d_ws + needT);

    // zero the never-touched rho bins once per call (also covers len==0 bins)
    hipMemsetAsync(d_out, 0, (size_t)out_size * sizeof(float), stream);

    if (fast) {
        transpose_k<<<dim3(WDIM / 32, HDIM / 32, B), dim3(32, 8), 0, stream>>>(mask, maskT);
        angles_k<<<1, 128, 0, stream>>>(tab);
        hough_lds_k<<<nba, TPB, 0, stream>>>(mask, maskT, tab, out);
    } else {
        int nthreads = nba * FB_GRP;
        hough_fb_k<<<(nthreads + 255) / 256, 256, 0, stream>>>(mask, out, nba);
    }
}